// Round 14
// baseline (3716.544 us; speedup 1.0000x reference)
//
#include <hip/hip_runtime.h>
#include <hip/hip_cooperative_groups.h>

#define V_    32000
#define B_    32
#define T_    128
#define H_    1024
#define BT_   4096     // B_*T_
#define G4H_  4096     // 4*H_
#define EPS_  1e-5f
#define FB_   1.0f     // forget bias

typedef __bf16  bf16x8 __attribute__((ext_vector_type(8)));
typedef float   f32x4  __attribute__((ext_vector_type(4)));
typedef float   f32x2  __attribute__((ext_vector_type(2)));
typedef unsigned u32x2 __attribute__((ext_vector_type(2)));
typedef short   short8 __attribute__((ext_vector_type(8)));

__device__ __forceinline__ unsigned short f2bf(float f) {
  unsigned u = __builtin_bit_cast(unsigned, f);
  u = u + 0x7FFFu + ((u >> 16) & 1u);          // round-to-nearest-even
  return (unsigned short)(u >> 16);
}
__device__ __forceinline__ float sigm(float x) { return 1.0f / (1.0f + expf(-x)); }

// ---------------------------------------------------------------- LLC-coherent access
__device__ __forceinline__ short8 ldg_coh16(const unsigned short* p) {
  short8 v;
  asm volatile("global_load_dwordx4 %0, %1, off sc0 sc1" : "=v"(v) : "v"(p) : "memory");
  return v;
}
__device__ __forceinline__ f32x4 ldg_coh16f(const float* p) {
  f32x4 v;
  asm volatile("global_load_dwordx4 %0, %1, off sc0 sc1" : "=v"(v) : "v"(p) : "memory");
  return v;
}
__device__ __forceinline__ void stg_coh8f(float* p, f32x2 v) {
  asm volatile("global_store_dwordx2 %0, %1, off sc0 sc1" :: "v"(p), "v"(v) : "memory");
}
__device__ __forceinline__ void stg_coh16f(float* p, f32x4 v) {
  asm volatile("global_store_dwordx4 %0, %1, off sc0 sc1" :: "v"(p), "v"(v) : "memory");
}
__device__ __forceinline__ void stg_coh8u(unsigned short* p, u32x2 v) {
  asm volatile("global_store_dwordx2 %0, %1, off sc0 sc1" :: "v"(p), "v"(v) : "memory");
}
__device__ __forceinline__ void vmwait0() {
  asm volatile("s_waitcnt vmcnt(0)" ::: "memory");
  __builtin_amdgcn_sched_barrier(0);           // rule #18: pin consumers after the wait
}

// ---------------------------------------------------------------- dataflow flag sync
__device__ __forceinline__ void wait_flags(unsigned* flags, int nslots, unsigned tgt) {
  const int lane = threadIdx.x & 63;
  for (;;) {
    unsigned v = 0xFFFFFFFFu;
    for (int s = lane; s < nslots; s += 64) {
      const unsigned x = __hip_atomic_load(&flags[16 * s], __ATOMIC_RELAXED, __HIP_MEMORY_SCOPE_AGENT);
      v = x < v ? x : v;
    }
    if (__all((int)(v >= tgt))) break;
    __builtin_amdgcn_s_sleep(1);
  }
}

// ---------------------------------------------------------------- transpose+cast
__global__ void k_transpose_cast(const float* __restrict__ in, unsigned short* __restrict__ out,
                                 int R, int C, int ldin) {
  __shared__ float tl[32][33];
  const int tx = threadIdx.x, ty = threadIdx.y;
  const int r0 = blockIdx.y * 32, c0 = blockIdx.x * 32;
#pragma unroll
  for (int i = 0; i < 4; ++i)
    tl[ty + 8 * i][tx] = in[(size_t)(r0 + ty + 8 * i) * ldin + c0 + tx];
  __syncthreads();
#pragma unroll
  for (int i = 0; i < 4; ++i)
    out[(size_t)(c0 + ty + 8 * i) * R + r0 + tx] = f2bf(tl[tx][ty + 8 * i]);
}

// ---------------------------------------------------------------- embedding gather
__global__ void k_gather(const int* __restrict__ ids, const float* __restrict__ emb,
                         unsigned short* __restrict__ x) {
  const int r = blockIdx.x;
  const int t4 = threadIdx.x * 4;
  const int row = ids[r];
  const float4 v = *(const float4*)&emb[(size_t)row * H_ + t4];
  ushort4 o;
  o.x = f2bf(v.x); o.y = f2bf(v.y); o.z = f2bf(v.z); o.w = f2bf(v.w);
  *(ushort4*)&x[(size_t)r * H_ + t4] = o;
}

// ---------------------------------------------------------------- bf16 GEMM (fallback path)
__global__ __launch_bounds__(256)
void k_gemm_bt(const unsigned short* __restrict__ A, const unsigned short* __restrict__ BT,
               const float* __restrict__ bias, float* __restrict__ C,
               int M, int N, int K, float* __restrict__ lse_part) {
  __shared__ unsigned short As[128 * 32];
  __shared__ unsigned short Bs[128 * 32];
  const int tid = threadIdx.x;
  const int lane = tid & 63, wid = tid >> 6;
  const int wr = wid >> 1, wc = wid & 1;
  const int la = lane & 15, lb = lane >> 4;

  int flat = blockIdx.y * gridDim.x + blockIdx.x;
  const int nwg = gridDim.x * gridDim.y;
  const int cpx = nwg >> 3;
  flat = (flat & 7) * cpx + (flat >> 3);
  const int bx = flat % gridDim.x, by = flat / gridDim.x;
  const int m0 = by * 128, n0 = bx * 128;

  f32x4 acc[4][4];
#pragma unroll
  for (int i = 0; i < 4; ++i)
#pragma unroll
    for (int j = 0; j < 4; ++j) acc[i][j] = f32x4{0.f, 0.f, 0.f, 0.f};

  for (int k0 = 0; k0 < K; k0 += 32) {
    __syncthreads();
#pragma unroll
    for (int i = 0; i < 2; ++i) {
      const int off = i * 2048 + tid * 8;
      const int row = off >> 5, col = off & 31;
      __builtin_amdgcn_global_load_lds(
          (const __attribute__((address_space(1))) void*)&A[(size_t)(m0 + row) * K + k0 + col],
          (__attribute__((address_space(3))) void*)&As[off], 16, 0, 0);
      __builtin_amdgcn_global_load_lds(
          (const __attribute__((address_space(1))) void*)&BT[(size_t)(n0 + row) * K + k0 + col],
          (__attribute__((address_space(3))) void*)&Bs[off], 16, 0, 0);
    }
    __syncthreads();
    bf16x8 a[4], b[4];
#pragma unroll
    for (int mm = 0; mm < 4; ++mm) a[mm] = *(bf16x8*)&As[(wr * 64 + mm * 16 + la) * 32 + lb * 8];
#pragma unroll
    for (int nn = 0; nn < 4; ++nn) b[nn] = *(bf16x8*)&Bs[(wc * 64 + nn * 16 + la) * 32 + lb * 8];
#pragma unroll
    for (int mm = 0; mm < 4; ++mm)
#pragma unroll
      for (int nn = 0; nn < 4; ++nn)
        acc[mm][nn] = __builtin_amdgcn_mfma_f32_16x16x32_bf16(a[mm], b[nn], acc[mm][nn], 0, 0, 0);
  }
#pragma unroll
  for (int mm = 0; mm < 4; ++mm)
#pragma unroll
    for (int nn = 0; nn < 4; ++nn) {
      const int row = m0 + wr * 64 + mm * 16 + lb * 4;
      const int col = n0 + wc * 64 + nn * 16 + la;
      const float bs = bias ? bias[col] : 0.f;
#pragma unroll
      for (int r = 0; r < 4; ++r)
        C[(size_t)(row + r) * N + col] = acc[mm][nn][r] + bs;
    }

  if (lse_part) {
#pragma unroll
    for (int mm = 0; mm < 4; ++mm)
#pragma unroll
      for (int r = 0; r < 4; ++r) {
        float vv[4];
        float mx = -1e30f;
#pragma unroll
        for (int nn = 0; nn < 4; ++nn) {
          vv[nn] = acc[mm][nn][r] + (bias ? bias[n0 + wc * 64 + nn * 16 + la] : 0.f);
          mx = fmaxf(mx, vv[nn]);
        }
        float ss = 0.f;
#pragma unroll
        for (int nn = 0; nn < 4; ++nn) ss += __expf(vv[nn] - mx);
#pragma unroll
        for (int msk = 1; msk < 16; msk <<= 1) {
          const float m2 = __shfl_xor(mx, msk);
          const float s2 = __shfl_xor(ss, msk);
          const float nm = fmaxf(mx, m2);
          ss = ss * __expf(mx - nm) + s2 * __expf(m2 - nm);
          mx = nm;
        }
        if (la == 0) {
          const int row = m0 + wr * 64 + mm * 16 + lb * 4 + r;
          *(float2*)&lse_part[((size_t)row * 512 + (size_t)bx * 2 + wc) * 2] = float2{mx, ss};
        }
      }
  }
}

// ---------------------------------------------------------------- shared LN+pointwise body
__device__ __forceinline__ void lstm_pointwise(
    const float* gfp, const float* g_, const float* b_, float* crow, float* rsc,
    unsigned short* hout, int tid, int lane, int w) {
  const int e0 = tid * 4;
  const f32x4 iv = ldg_coh16f(&gfp[e0]);
  const f32x4 jv = ldg_coh16f(&gfp[1024 + e0]);
  const f32x4 fv = ldg_coh16f(&gfp[2048 + e0]);
  const f32x4 ov = ldg_coh16f(&gfp[3072 + e0]);
  vmwait0();

  float vals[8] = {0, 0, 0, 0, 0, 0, 0, 0};
#pragma unroll
  for (int u = 0; u < 4; ++u) {
    vals[0] += iv[u]; vals[4] += iv[u] * iv[u];
    vals[1] += jv[u]; vals[5] += jv[u] * jv[u];
    vals[2] += fv[u]; vals[6] += fv[u] * fv[u];
    vals[3] += ov[u]; vals[7] += ov[u] * ov[u];
  }
#pragma unroll
  for (int i = 0; i < 8; ++i) {
    float x = vals[i];
    for (int off = 32; off > 0; off >>= 1) x += __shfl_down(x, off);
    if (lane == 0) rsc[w * 8 + i] = x;
  }
  __syncthreads();
#pragma unroll
  for (int i = 0; i < 8; ++i)
    vals[i] = rsc[i] + rsc[8 + i] + rsc[16 + i] + rsc[24 + i];
  __syncthreads();
  const float m0 = vals[0] * (1.f / 1024), m1 = vals[1] * (1.f / 1024);
  const float m2 = vals[2] * (1.f / 1024), m3 = vals[3] * (1.f / 1024);
  const float r0 = rsqrtf(vals[4] * (1.f / 1024) - m0 * m0 + EPS_);
  const float r1 = rsqrtf(vals[5] * (1.f / 1024) - m1 * m1 + EPS_);
  const float r2 = rsqrtf(vals[6] * (1.f / 1024) - m2 * m2 + EPS_);
  const float r3 = rsqrtf(vals[7] * (1.f / 1024) - m3 * m3 + EPS_);

  const float4 gI = *(const float4*)&g_[e0];
  const float4 gJ = *(const float4*)&g_[1024 + e0];
  const float4 gF = *(const float4*)&g_[2048 + e0];
  const float4 gO = *(const float4*)&g_[3072 + e0];
  const float4 gC = *(const float4*)&g_[4096 + e0];
  const float4 bI = *(const float4*)&b_[e0];
  const float4 bJ = *(const float4*)&b_[1024 + e0];
  const float4 bF = *(const float4*)&b_[2048 + e0];
  const float4 bO = *(const float4*)&b_[3072 + e0];
  const float4 bC = *(const float4*)&b_[4096 + e0];
  const float4 cr = *(const float4*)&crow[e0];

  float nc[4], oo[4];
  float cs = 0.f, cq = 0.f;
  {
    const float gi[4] = {gI.x, gI.y, gI.z, gI.w}, bi[4] = {bI.x, bI.y, bI.z, bI.w};
    const float gj[4] = {gJ.x, gJ.y, gJ.z, gJ.w}, bj[4] = {bJ.x, bJ.y, bJ.z, bJ.w};
    const float gff[4] = {gF.x, gF.y, gF.z, gF.w}, bf[4] = {bF.x, bF.y, bF.z, bF.w};
    const float go[4] = {gO.x, gO.y, gO.z, gO.w}, bo[4] = {bO.x, bO.y, bO.z, bO.w};
    const float cv[4] = {cr.x, cr.y, cr.z, cr.w};
#pragma unroll
    for (int u = 0; u < 4; ++u) {
      const float xi = gi[u] * ((iv[u] - m0) * r0) + bi[u];
      const float xj = gj[u] * ((jv[u] - m1) * r1) + bj[u];
      const float xf = gff[u] * ((fv[u] - m2) * r2) + bf[u];
      const float xo = go[u] * ((ov[u] - m3) * r3) + bo[u];
      const float ncv = cv[u] * sigm(xf + FB_) + sigm(xi) * tanhf(xj);
      nc[u] = ncv; oo[u] = xo;
      cs += ncv; cq += ncv * ncv;
    }
  }
  {
    float x = cs, y = cq;
    for (int off = 32; off > 0; off >>= 1) { x += __shfl_down(x, off); y += __shfl_down(y, off); }
    if (lane == 0) { rsc[w * 2] = x; rsc[w * 2 + 1] = y; }
  }
  __syncthreads();
  cs = rsc[0] + rsc[2] + rsc[4] + rsc[6];
  cq = rsc[1] + rsc[3] + rsc[5] + rsc[7];
  const float mc = cs * (1.f / 1024);
  const float rc = rsqrtf(cq * (1.f / 1024) - mc * mc + EPS_);
  {
    const float gc[4] = {gC.x, gC.y, gC.z, gC.w}, bc[4] = {bC.x, bC.y, bC.z, bC.w};
    unsigned short hb[4];
#pragma unroll
    for (int u = 0; u < 4; ++u) {
      const float nh = tanhf(gc[u] * ((nc[u] - mc) * rc) + bc[u]) * sigm(oo[u]);
      hb[u] = f2bf(nh);
    }
    u32x2 hv;
    hv[0] = (unsigned)hb[0] | ((unsigned)hb[1] << 16);
    hv[1] = (unsigned)hb[2] | ((unsigned)hb[3] << 16);
    stg_coh8u(&hout[e0], hv);
    *(float4*)&crow[e0] = float4{nc[0], nc[1], nc[2], nc[3]};
  }
  __syncthreads();                           // drain h stores before flag
}

// ---------------------------------------------------------------- k_lstm4: layer-split LSTM + in-kernel projection
// Blocks 0-63:    L0, 64 gate-cols each (Wh0 128KB in wbuf), 2-pass reduce.
// Blocks 64-191:  L1, 32 cols each (Wx1 in wbuf[0,64K), Wh1 in wbuf[64K,128K)).
// Blocks 192-255: projection. Block pb owns nts {pb, pb+64, pb+128, pb+192}<250
//   of EVERY t-group tg (rows b*128+4tg..+3), gated by flag_h1 >= 4tg+4.
//   A reg-staged via sc-loads from Hb1 (coherent with P2-L1's sc-stores+flags);
//   B via global_load_lds from WsT. Per-row online LSE in LDS, flushed per tg to
//   part[row*128 + pb*2 + wc] (float2). Static ownership -> deterministic.
// Flags: g0[64]@0, g1[128]@+2048w, h0[32]@+4096w, h1[32]@+4608w.
__global__ __launch_bounds__(256)
void k_lstm4(const float* __restrict__ G, const unsigned short* __restrict__ WhT0,
             const unsigned short* __restrict__ WxT1, const unsigned short* __restrict__ WhT1,
             const float* __restrict__ b1,
             const float* __restrict__ lng, const float* __restrict__ lnb,
             float* __restrict__ gf0, float* __restrict__ gf1,
             unsigned short* __restrict__ Hb0, unsigned short* __restrict__ Hb1,
             unsigned* flags,
             const unsigned short* __restrict__ WsT, const float* __restrict__ sb,
             float* __restrict__ Cout, float* __restrict__ part) {
  __shared__ unsigned short wbuf[64 * 1024];  // 128 KB, role depends on block
  __shared__ float red[4][32][32];            // 16 KB
  __shared__ float crow[1024];                // 4 KB
  __shared__ float rsc[64];

  const int tid = threadIdx.x, bid = blockIdx.x;
  const int lane = tid & 63, w = tid >> 6;
  const int la = lane & 15, lb = lane >> 4;
  const int wr = (tid >> 6) >> 1, wc = (tid >> 6) & 1;
  unsigned* flag_g0 = flags;                  // 64 slots
  unsigned* flag_g1 = flags + 2048;           // 128 slots
  unsigned* flag_h0 = flags + 4096;           // 32 slots
  unsigned* flag_h1 = flags + 4608;           // 32 slots

  // ================================================== projection blocks
  if (bid >= 192) {
    const int pb = bid - 192;
    float* runm = (float*)&wbuf[8192];        // [2][128] (wc-major)
    float* runs = runm + 256;
    for (int tg = 0; tg < 32; ++tg) {
      for (int i = tid; i < 256; i += 256) { runm[i] = -1e30f; runs[i] = 0.f; }
      if (w == 0) wait_flags(flag_h1, 32, (unsigned)(4 * tg + 4));
      __syncthreads();
      for (int nt = pb; nt < 250; nt += 64) {
        const int n0 = nt * 128;
        f32x4 acc[4][4];
#pragma unroll
        for (int i = 0; i < 4; ++i)
#pragma unroll
          for (int j = 0; j < 4; ++j) acc[i][j] = f32x4{0.f, 0.f, 0.f, 0.f};
        for (int k0 = 0; k0 < 1024; k0 += 32) {
          __syncthreads();
          short8 tA0, tA1;
          {
            const int off0 = tid * 8, off1 = 2048 + tid * 8;
            const int r0 = off0 >> 5, c0 = off0 & 31;
            const int r1 = off1 >> 5, c1 = off1 & 31;
            const int s0 = (r0 >> 2) * 128 + 4 * tg + (r0 & 3);
            const int s1 = (r1 >> 2) * 128 + 4 * tg + (r1 & 3);
            tA0 = ldg_coh16(&Hb1[(size_t)s0 * H_ + k0 + c0]);
            tA1 = ldg_coh16(&Hb1[(size_t)s1 * H_ + k0 + c1]);
#pragma unroll
            for (int i = 0; i < 2; ++i) {
              const int off = i * 2048 + tid * 8;
              const int row = off >> 5, col = off & 31;
              __builtin_amdgcn_global_load_lds(
                  (const __attribute__((address_space(1))) void*)&WsT[(size_t)(n0 + row) * H_ + k0 + col],
                  (__attribute__((address_space(3))) void*)&wbuf[4096 + off], 16, 0, 0);
            }
            vmwait0();
            *(short8*)&wbuf[off0] = tA0;
            *(short8*)&wbuf[2048 + tid * 8] = tA1;
          }
          __syncthreads();
          bf16x8 a[4], b[4];
#pragma unroll
          for (int mm = 0; mm < 4; ++mm) a[mm] = *(bf16x8*)&wbuf[(wr * 64 + mm * 16 + la) * 32 + lb * 8];
#pragma unroll
          for (int nn = 0; nn < 4; ++nn) b[nn] = *(bf16x8*)&wbuf[4096 + (wc * 64 + nn * 16 + la) * 32 + lb * 8];
#pragma unroll
          for (int mm = 0; mm < 4; ++mm)
#pragma unroll
            for (int nn = 0; nn < 4; ++nn)
              acc[mm][nn] = __builtin_amdgcn_mfma_f32_16x16x32_bf16(a[mm], b[nn], acc[mm][nn], 0, 0, 0);
        }
        // epilogue: C write (+bias) and per-row online-LSE update
#pragma unroll
        for (int mm = 0; mm < 4; ++mm)
#pragma unroll
          for (int r = 0; r < 4; ++r) {
            const int rowp = wr * 64 + mm * 16 + lb * 4 + r;
            const int grow = (rowp >> 2) * 128 + 4 * tg + (rowp & 3);
            float vv[4];
            float mx = -1e30f;
#pragma unroll
            for (int nn = 0; nn < 4; ++nn) {
              const int col = n0 + wc * 64 + nn * 16 + la;
              vv[nn] = acc[mm][nn][r] + sb[col];
              Cout[(size_t)grow * V_ + col] = vv[nn];
              mx = fmaxf(mx, vv[nn]);
            }
            float ss = 0.f;
#pragma unroll
            for (int nn = 0; nn < 4; ++nn) ss += __expf(vv[nn] - mx);
#pragma unroll
            for (int msk = 1; msk < 16; msk <<= 1) {
              const float m2 = __shfl_xor(mx, msk);
              const float s2 = __shfl_xor(ss, msk);
              const float nm = fmaxf(mx, m2);
              ss = ss * __expf(mx - nm) + s2 * __expf(m2 - nm);
              mx = nm;
            }
            if (la == 0) {
              const int idx = wc * 128 + rowp;
              const float om = runm[idx], os = runs[idx];
              const float nm = fmaxf(om, mx);
              runs[idx] = os * __expf(om - nm) + ss * __expf(mx - nm);
              runm[idx] = nm;
            }
          }
      }
      __syncthreads();
      if (tid < 128) {
        const int grow = (tid >> 2) * 128 + 4 * tg + (tid & 3);
        *(float2*)&part[((size_t)grow * 128 + pb * 2 + 0) * 2] = float2{runm[tid], runs[tid]};
        *(float2*)&part[((size_t)grow * 128 + pb * 2 + 1) * 2] = float2{runm[128 + tid], runs[128 + tid]};
      }
      __syncthreads();
    }
    return;
  }

  // ================================================== LSTM blocks
  const bool isL1 = (bid >= 64);
  const int cb = isL1 ? (bid - 64) * 32 : bid * 64;

  // stage weights (swizzled rows)
  if (!isL1) {
    for (int i = tid * 8; i < 64 * 1024; i += 2048) {
      const int cl = i >> 10, k = i & 1023;
      *(short8*)&wbuf[cl * 1024 + (k ^ ((cl & 7) << 3))] = *(const short8*)&WhT0[(size_t)(cb + cl) * 1024 + k];
    }
  } else {
    for (int i = tid * 8; i < 32 * 1024; i += 2048) {
      const int cl = i >> 10, k = i & 1023;
      const int dst = cl * 1024 + (k ^ ((cl & 7) << 3));
      *(short8*)&wbuf[dst] = *(const short8*)&WxT1[(size_t)(cb + cl) * 1024 + k];
      *(short8*)&wbuf[32 * 1024 + dst] = *(const short8*)&WhT1[(size_t)(cb + cl) * 1024 + k];
    }
  }
  if (bid < 32 || (bid >= 64 && bid < 96))
    for (int e = tid; e < 1024; e += 256) crow[e] = 0.0f;
  __syncthreads();

  for (int s = 0; s <= T_; ++s) {
    if (w == 0) {
      if (!isL1) {
        if (s >= 1 && s < T_) wait_flags(flag_h0, 32, (unsigned)s);
      } else {
        if (s >= 1) wait_flags(flag_h0, 32, (unsigned)s);
        if (s >= 2) wait_flags(flag_h1, 32, (unsigned)(s - 1));
      }
    }
    __syncthreads();

    if (!isL1) {
      // -------- L0: 64 cols, acc[2 row-halves][4 col-groups]
      f32x4 acc[2][4];
#pragma unroll
      for (int i = 0; i < 2; ++i)
#pragma unroll
        for (int j = 0; j < 4; ++j) acc[i][j] = f32x4{0.f, 0.f, 0.f, 0.f};
      if (s >= 1 && s < T_) {
        const int kw = w * 256 + lb * 8;
        const size_t t0 = (size_t)(s - 1);
#pragma unroll
        for (int half = 0; half < 2; ++half) {
          short8 a0[4], a1[4];
          const int kb = kw + half * 128;
#pragma unroll
          for (int kk = 0; kk < 4; ++kk) {
            a0[kk] = ldg_coh16(&Hb0[((size_t)la * T_ + t0) * H_ + kb + kk * 32]);
            a1[kk] = ldg_coh16(&Hb0[((size_t)(16 + la) * T_ + t0) * H_ + kb + kk * 32]);
          }
          vmwait0();
#pragma unroll
          for (int kk = 0; kk < 4; ++kk) {
            const int kx = (kb + kk * 32) ^ ((la & 7) << 3);
            const bf16x8 va0 = __builtin_bit_cast(bf16x8, a0[kk]);
            const bf16x8 va1 = __builtin_bit_cast(bf16x8, a1[kk]);
#pragma unroll
            for (int cg = 0; cg < 4; ++cg) {
              const bf16x8 bv = *(bf16x8*)&wbuf[(cg * 16 + la) * 1024 + kx];
              acc[0][cg] = __builtin_amdgcn_mfma_f32_16x16x32_bf16(va0, bv, acc[0][cg], 0, 0, 0);
              acc[1][cg] = __builtin_amdgcn_mfma_f32_16x16x32_bf16(va1, bv, acc[1][cg], 0, 0, 0);
            }
          }
        }
      }
      if (s < T_) {
        // 2-pass reduce over 64 cols (red is 32-wide)
#pragma unroll
        for (int p = 0; p < 2; ++p) {
#pragma unroll
          for (int rh = 0; rh < 2; ++rh)
#pragma unroll
            for (int cg2 = 0; cg2 < 2; ++cg2)
#pragma unroll
              for (int r = 0; r < 4; ++r)
                red[w][rh * 16 + lb * 4 + r][cg2 * 16 + la] = acc[rh][p * 2 + cg2][r];
          __syncthreads();
          {
            const int b2 = tid >> 3, c4 = (tid & 7) * 4;
            f32x4 sv = *(f32x4*)&red[0][b2][c4];
            sv += *(f32x4*)&red[1][b2][c4];
            sv += *(f32x4*)&red[2][b2][c4];
            sv += *(f32x4*)&red[3][b2][c4];
            sv += *(const f32x4*)&G[((size_t)(b2 * T_ + s)) * G4H_ + cb + p * 32 + c4];
            stg_coh16f(&gf0[(size_t)b2 * G4H_ + cb + p * 32 + c4], sv);
          }
          __syncthreads();
        }
        if (tid == 0)
          __hip_atomic_store(&flag_g0[16 * bid], (unsigned)(s + 1), __ATOMIC_RELAXED, __HIP_MEMORY_SCOPE_AGENT);
      }
      // P2-L0
      if (bid < 32 && s < T_) {
        if (w == 0) wait_flags(flag_g0, 64, (unsigned)(s + 1));
        __syncthreads();
        lstm_pointwise(gf0 + (size_t)bid * G4H_, lng, lnb, crow, rsc,
                       Hb0 + ((size_t)bid * T_ + s) * H_, tid, lane, w);
        if (tid == 0)
          __hip_atomic_store(&flag_h0[16 * bid], (unsigned)(s + 1), __ATOMIC_RELAXED, __HIP_MEMORY_SCOPE_AGENT);
      }
    } else {
      // -------- L1: 32 cols, Wx1 + Wh1
      f32x4 acc[2][2] = {{{0.f,0.f,0.f,0.f},{0.f,0.f,0.f,0.f}},{{0.f,0.f,0.f,0.f},{0.f,0.f,0.f,0.f}}};
      if (s >= 1) {
        const int kw = w * 256 + lb * 8;
        const size_t t0 = (size_t)(s - 1);
        const size_t t1 = (size_t)(s - 2);
#pragma unroll
        for (int half = 0; half < 2; ++half) {
          short8 a0[4], a1[4];
          const int kb = kw + half * 128;
#pragma unroll
          for (int kk = 0; kk < 4; ++kk) {
            a0[kk] = ldg_coh16(&Hb0[((size_t)la * T_ + t0) * H_ + kb + kk * 32]);
            a1[kk] = ldg_coh16(&Hb0[((size_t)(16 + la) * T_ + t0) * H_ + kb + kk * 32]);
          }
          vmwait0();
#pragma unroll
          for (int kk = 0; kk < 4; ++kk) {
            const int kx = (kb + kk * 32) ^ ((la & 7) << 3);
            const bf16x8 b0 = *(bf16x8*)&wbuf[(la) * 1024 + kx];
            const bf16x8 b1v = *(bf16x8*)&wbuf[(16 + la) * 1024 + kx];
            const bf16x8 va0 = __builtin_bit_cast(bf16x8, a0[kk]);
            const bf16x8 va1 = __builtin_bit_cast(bf16x8, a1[kk]);
            acc[0][0] = __builtin_amdgcn_mfma_f32_16x16x32_bf16(va0, b0, acc[0][0], 0, 0, 0);
            acc[0][1] = __builtin_amdgcn_mfma_f32_16x16x32_bf16(va0, b1v, acc[0][1], 0, 0, 0);
            acc[1][0] = __builtin_amdgcn_mfma_f32_16x16x32_bf16(va1, b0, acc[1][0], 0, 0, 0);
            acc[1][1] = __builtin_amdgcn_mfma_f32_16x16x32_bf16(va1, b1v, acc[1][1], 0, 0, 0);
          }
        }
        if (s >= 2) {
#pragma unroll
          for (int half = 0; half < 2; ++half) {
            short8 a0[4], a1[4];
            const int kb = kw + half * 128;
#pragma unroll
            for (int kk = 0; kk < 4; ++kk) {
              a0[kk] = ldg_coh16(&Hb1[((size_t)la * T_ + t1) * H_ + kb + kk * 32]);
              a1[kk] = ldg_coh16(&Hb1[((size_t)(16 + la) * T_ + t1) * H_ + kb + kk * 32]);
            }
            vmwait0();
#pragma unroll
            for (int kk = 0; kk < 4; ++kk) {
              const int kx = (kb + kk * 32) ^ ((la & 7) << 3);
              const bf16x8 b0 = *(bf16x8*)&wbuf[32 * 1024 + (la) * 1024 + kx];
              const bf16x8 b1v = *(bf16x8*)&wbuf[32 * 1024 + (16 + la) * 1024 + kx];
              const bf16x8 va0 = __builtin_bit_cast(bf16x8, a0[kk]);
              const bf16x8 va1 = __builtin_bit_cast(bf16x8, a1[kk]);
              acc[0][0] = __builtin_amdgcn_mfma_f32_16x16x32_bf16(va0, b0, acc[0][0], 0, 0, 0);
              acc[0][1] = __builtin_amdgcn_mfma_f32_16x16x32_bf16(va0, b1v, acc[0][1], 0, 0, 0);
              acc[1][0] = __builtin_amdgcn_mfma_f32_16x16x32_bf16(va1, b0, acc[1][0], 0, 0, 0);
              acc[1][1] = __builtin_amdgcn_mfma_f32_16x16x32_bf16(va1, b1v, acc[1][1], 0, 0, 0);
            }
          }
        }
      }
      if (s >= 1) {
#pragma unroll
        for (int rh = 0; rh < 2; ++rh)
#pragma unroll
          for (int cg = 0; cg < 2; ++cg)
#pragma unroll
            for (int r = 0; r < 4; ++r)
              red[w][rh * 16 + lb * 4 + r][cg * 16 + la] = acc[rh][cg][r];
        __syncthreads();
        {
          const int b2 = tid >> 3, c4 = (tid & 7) * 4;
          f32x4 sv = *(f32x4*)&red[0][b2][c4];
          sv += *(f32x4*)&red[1][b2][c4];
          sv += *(f32x4*)&red[2][b2][c4];
          sv += *(f32x4*)&red[3][b2][c4];
          sv += *(const f32x4*)&b1[cb + c4];
          stg_coh16f(&gf1[(size_t)b2 * G4H_ + cb + c4], sv);
        }
        __syncthreads();
        if (tid == 0)
          __hip_atomic_store(&flag_g1[16 * (bid - 64)], (unsigned)(s + 1), __ATOMIC_RELAXED, __HIP_MEMORY_SCOPE_AGENT);
      }
      // P2-L1
      if (bid < 96 && s >= 1) {
        const int b = bid - 64;
        if (w == 0) wait_flags(flag_g1, 128, (unsigned)(s + 1));
        __syncthreads();
        lstm_pointwise(gf1 + (size_t)b * G4H_, lng + 5120, lnb + 5120, crow, rsc,
                       Hb1 + ((size_t)b * T_ + (s - 1)) * H_, tid, lane, w);
        if (tid == 0)
          __hip_atomic_store(&flag_h1[16 * b], (unsigned)s, __ATOMIC_RELAXED, __HIP_MEMORY_SCOPE_AGENT);
      }
    }
  }
}

// ---------------------------------------------------------------- k_lstm3 (r13-proven fallback)
__global__ __launch_bounds__(256)
void k_lstm3(const float* __restrict__ G, const unsigned short* __restrict__ WhT0,
             const unsigned short* __restrict__ WxT1, const unsigned short* __restrict__ WhT1,
             const float* __restrict__ b1,
             const float* __restrict__ lng, const float* __restrict__ lnb,
             float* __restrict__ gf0, float* __restrict__ gf1,
             unsigned short* __restrict__ Hb0, unsigned short* __restrict__ Hb1,
             unsigned* flags) {
  __shared__ unsigned short wA[32 * 1024];
  __shared__ unsigned short wB[32 * 1024];
  __shared__ float red[4][32][32];
  __shared__ float crow[1024];
  __shared__ float rsc[64];

  const int tid = threadIdx.x, bid = blockIdx.x;
  const int lane = tid & 63, w = tid >> 6;
  const int la = lane & 15, lb = lane >> 4;
  const bool isL1 = (bid >= 128);
  const int cb = (isL1 ? (bid - 128) : bid) * 32;
  unsigned* flag_g0 = flags;
  unsigned* flag_g1 = flags + 2048;
  unsigned* flag_h0 = flags + 4096;
  unsigned* flag_h1 = flags + 4608;

  for (int i = tid * 8; i < 32 * 1024; i += 2048) {
    const int cl = i >> 10, k = i & 1023;
    const int dst = cl * 1024 + (k ^ ((cl & 7) << 3));
    if (!isL1) {
      *(short8*)&wA[dst] = *(const short8*)&WhT0[(size_t)(cb + cl) * 1024 + k];
    } else {
      *(short8*)&wA[dst] = *(const short8*)&WxT1[(size_t)(cb + cl) * 1024 + k];
      *(short8*)&wB[dst] = *(const short8*)&WhT1[(size_t)(cb + cl) * 1024 + k];
    }
  }
  if (bid < 32 || (bid >= 128 && bid < 160))
    for (int e = tid; e < 1024; e += 256) crow[e] = 0.0f;
  __syncthreads();

  for (int s = 0; s <= T_; ++s) {
    if (w == 0) {
      if (!isL1) {
        if (s >= 1 && s < T_) wait_flags(flag_h0, 32, (unsigned)s);
      } else {
        if (s >= 1) wait_flags(flag_h0, 32, (unsigned)s);
        if (s >= 2) wait_flags(flag_h1, 32, (unsigned)(s - 1));
      }
    }
    __syncthreads();

    f32x4 acc[2][2] = {{{0.f,0.f,0.f,0.f},{0.f,0.f,0.f,0.f}},{{0.f,0.f,0.f,0.f},{0.f,0.f,0.f,0.f}}};
    const int kw = w * 256 + lb * 8;
    if (!isL1) {
      if (s >= 1 && s < T_) {
        const size_t t0 = (size_t)(s - 1);
#pragma unroll
        for (int half = 0; half < 2; ++half) {
          short8 a0[4], a1[4];
          const int kb = kw + half * 128;
#pragma unroll
          for (int kk = 0; kk < 4; ++kk) {
            a0[kk] = ldg_coh16(&Hb0[((size_t)la * T_ + t0) * H_ + kb + kk * 32]);
            a1[kk] = ldg_coh16(&Hb0[((size_t)(16 + la) * T_ + t0) * H_ + kb + kk * 32]);
          }
          vmwait0();
#pragma unroll
          for (int kk = 0; kk < 4; ++kk) {
            const int kx = (kb + kk * 32) ^ ((la & 7) << 3);
            const bf16x8 b0 = *(bf16x8*)&wA[la * 1024 + kx];
            const bf16x8 b1v = *(bf16x8*)&wA[(16 + la) * 1024 + kx];
            const bf16x8 va0 = __builtin_bit_cast(bf16x8, a0[kk]);
            const bf16x8 va1 = __builtin_bit_cast(bf16x8, a1[kk]);
            acc[0][0] = __builtin_amdgcn_mfma_f32_16x16x32_bf16(va0, b0, acc[0][0], 0, 0, 0);
            acc[0][1] = __builtin_amdgcn_mfma_f32_16x16x32_bf16(va0, b1v, acc[0][1], 0, 0, 0);
            acc[1][0] = __builtin_amdgcn_mfma_f32_16x16x32_bf16(va1, b0, acc[1][0], 0, 0, 0);
            acc[1][1] = __builtin_amdgcn_mfma_f32_16x16x32_bf16(va1, b1v, acc[1][1], 0, 0, 0);
          }
        }
      }
    } else if (s >= 1) {
      const size_t t0 = (size_t)(s - 1);
#pragma unroll
      for (int half = 0; half < 2; ++half) {
        short8 a0[4], a1[4];
        const int kb = kw + half * 128;
#pragma unroll
        for (int kk = 0; kk < 4; ++kk) {
          a0[kk] = ldg_coh16(&Hb0[((size_t)la * T_ + t0) * H_ + kb + kk * 32]);
          a1[kk] = ldg_coh16(&Hb0[((size_t)(16 + la) * T_ + t0) * H_ + kb + kk * 32]);
        }
        vmwait0();
#pragma unroll
        for (int kk = 0; kk < 4; ++kk) {
          const int kx = (kb + kk * 32) ^ ((la & 7) << 3);
          const bf16x8 b0 = *(bf16x8*)&wA[la * 1024 + kx];
          const bf16x8 b1v = *(bf16x8*)&wA[(16 + la) * 1024 + kx];
          const bf16x8 va0 = __builtin_bit_cast(bf16x8, a0[kk]);
          const bf16x8 va1 = __builtin_bit_cast(bf16x8, a1[kk]);
          acc[0][0] = __builtin_amdgcn_mfma_f32_16x16x32_bf16(va0, b0, acc[0][0], 0, 0, 0);
          acc[0][1] = __builtin_amdgcn_mfma_f32_16x16x32_bf16(va0, b1v, acc[0][1], 0, 0, 0);
          acc[1][0] = __builtin_amdgcn_mfma_f32_16x16x32_bf16(va1, b0, acc[1][0], 0, 0, 0);
          acc[1][1] = __builtin_amdgcn_mfma_f32_16x16x32_bf16(va1, b1v, acc[1][1], 0, 0, 0);
        }
      }
      if (s >= 2) {
        const size_t t1 = (size_t)(s - 2);
#pragma unroll
        for (int half = 0; half < 2; ++half) {
          short8 a0[4], a1[4];
          const int kb = kw + half * 128;
#pragma unroll
          for (int kk = 0; kk < 4; ++kk) {
            a0[kk] = ldg_coh16(&Hb1[((size_t)la * T_ + t1) * H_ + kb + kk * 32]);
            a1[kk] = ldg_coh16(&Hb1[((size_t)(16 + la) * T_ + t1) * H_ + kb + kk * 32]);
          }
          vmwait0();
#pragma unroll
          for (int kk = 0; kk < 4; ++kk) {
            const int kx = (kb + kk * 32) ^ ((la & 7) << 3);
            const bf16x8 b0 = *(bf16x8*)&wB[la * 1024 + kx];
            const bf16x8 b1v = *(bf16x8*)&wB[(16 + la) * 1024 + kx];
            const bf16x8 va0 = __builtin_bit_cast(bf16x8, a0[kk]);
            const bf16x8 va1 = __builtin_bit_cast(bf16x8, a1[kk]);
            acc[0][0] = __builtin_amdgcn_mfma_f32_16x16x32_bf16(va0, b0, acc[0][0], 0, 0, 0);
            acc[0][1] = __builtin_amdgcn_mfma_f32_16x16x32_bf16(va0, b1v, acc[0][1], 0, 0, 0);
            acc[1][0] = __builtin_amdgcn_mfma_f32_16x16x32_bf16(va1, b0, acc[1][0], 0, 0, 0);
            acc[1][1] = __builtin_amdgcn_mfma_f32_16x16x32_bf16(va1, b1v, acc[1][1], 0, 0, 0);
          }
        }
      }
    }

    const bool doStore = isL1 ? (s >= 1) : (s < T_);
    if (doStore) {
#pragma unroll
      for (int half = 0; half < 2; ++half)
#pragma unroll
        for (int cg = 0; cg < 2; ++cg)
#pragma unroll
          for (int r = 0; r < 4; ++r)
            red[w][half * 16 + lb * 4 + r][cg * 16 + la] = acc[half][cg][r];
      __syncthreads();
      const int b2 = tid >> 3, c4 = (tid & 7) * 4;
      f32x4 sv = *(f32x4*)&red[0][b2][c4];
      sv += *(f32x4*)&red[1][b2][c4];
      sv += *(f32x4*)&red[2][b2][c4];
      sv += *(f32x4*)&red[3][b2][c4];
      if (!isL1) {
        sv += *(const f32x4*)&G[((size_t)(b2 * T_ + s)) * G4H_ + cb + c4];
        stg_coh16f(&gf0[(size_t)b2 * G4H_ + cb + c4], sv);
      } else {
        sv += *(const f32x4*)&b1[cb + c4];
        stg_coh16f(&gf1[(size_t)b2 * G4H_ + cb + c4], sv);
      }
      __syncthreads();
      if (tid == 0) {
        if (!isL1)
          __hip_atomic_store(&flag_g0[16 * bid], (unsigned)(s + 1), __ATOMIC_RELAXED, __HIP_MEMORY_SCOPE_AGENT);
        else
          __hip_atomic_store(&flag_g1[16 * (bid - 128)], (unsigned)(s + 1), __ATOMIC_RELAXED, __HIP_MEMORY_SCOPE_AGENT);
      }
    }

    const bool doP2 = (!isL1) ? (bid < 32 && s < T_) : (bid < 160 && s >= 1);
    if (doP2) {
      const int b = isL1 ? (bid - 128) : bid;
      if (w == 0) wait_flags(isL1 ? flag_g1 : flag_g0, 128, (unsigned)(s + 1));
      __syncthreads();
      const float* gfp = (isL1 ? gf1 : gf0) + (size_t)b * G4H_;
      const float* g_ = isL1 ? (lng + 5120) : lng;
      const float* b_ = isL1 ? (lnb + 5120) : lnb;
      const int tt = isL1 ? (s - 1) : s;
      unsigned short* hout = (isL1 ? Hb1 : Hb0) + ((size_t)b * T_ + tt) * H_;
      lstm_pointwise(gfp, g_, b_, crow, rsc, hout, tid, lane, w);
      if (tid == 0) {
        if (isL1)
          __hip_atomic_store(&flag_h1[16 * b], (unsigned)s, __ATOMIC_RELAXED, __HIP_MEMORY_SCOPE_AGENT);
        else
          __hip_atomic_store(&flag_h0[16 * b], (unsigned)(s + 1), __ATOMIC_RELAXED, __HIP_MEMORY_SCOPE_AGENT);
      }
    }
  }
}

// ---------------------------------------------------------------- LSE finish (generic)
__global__ __launch_bounds__(256)
void k_lse_finishN(const float* __restrict__ part, float* __restrict__ lse,
                   int stride, int count) {
  __shared__ float rm[4];
  __shared__ float rs[4];
  const int r = blockIdx.x, tid = threadIdx.x;
  const int lane = tid & 63, w = tid >> 6;
  float m = -1e30f, s = 0.f;
  for (int i = tid; i < count; i += 256) {
    const float2 p = *(const float2*)&part[((size_t)r * stride + i) * 2];
    const float nm = fmaxf(m, p.x);
    s = s * __expf(m - nm) + p.y * __expf(p.x - nm);
    m = nm;
  }
  for (int off = 32; off > 0; off >>= 1) {
    const float m2 = __shfl_down(m, off), s2 = __shfl_down(s, off);
    const float nm = fmaxf(m, m2);
    s = s * __expf(m - nm) + s2 * __expf(m2 - nm);
    m = nm;
  }
  if (lane == 0) { rm[w] = m; rs[w] = s; }
  __syncthreads();
  if (tid == 0) {
    float M = rm[0], S = rs[0];
#pragma unroll
    for (int i = 1; i < 4; ++i) {
      const float nm = fmaxf(M, rm[i]);
      S = S * __expf(M - nm) + rs[i] * __expf(rm[i] - nm);
      M = nm;
    }
    lse[r] = M + logf(S);
  }
}

// ---------------------------------------------------------------- loss (mean NLL)
__global__ __launch_bounds__(256)
void k_loss(const float* __restrict__ logits, const float* __restrict__ lse,
            const int* __restrict__ tgt, float* __restrict__ out) {
  __shared__ float rsc[4];
  const int tid = threadIdx.x;
  float s = 0.f;
  for (int r = tid; r < BT_; r += 256)
    s += lse[r] - logits[(size_t)r * V_ + tgt[r]];
  for (int off = 32; off > 0; off >>= 1) s += __shfl_down(s, off);
  if ((tid & 63) == 0) rsc[tid >> 6] = s;
  __syncthreads();
  if (tid == 0) out[(size_t)BT_ * V_] = (rsc[0] + rsc[1] + rsc[2] + rsc[3]) / (float)BT_;
}

// ================================================================ launch
// k_lstm4 (LSTM + in-kernel projection) with CHECKED launch; fallback =
// r13-proven k_lstm3 + external projection GEMM.
extern "C" void kernel_launch(void* const* d_in, const int* in_sizes, int n_in,
                              void* d_out, int out_size, void* d_ws, size_t ws_size,
                              hipStream_t stream) {
  const int*   ids  = (const int*)d_in[0];
  const int*   tgt  = (const int*)d_in[1];
  const float* emb  = (const float*)d_in[2];
  const float* W    = (const float*)d_in[3];
  const float* brnn = (const float*)d_in[4];
  const float* lng  = (const float*)d_in[5];
  const float* lnb  = (const float*)d_in[6];
  const float* sw   = (const float*)d_in[7];
  const float* sb   = (const float*)d_in[8];
  float* out = (float*)d_out;

  char* ws = (char*)d_ws;
  size_t o = 0;
  auto take = [&](size_t n) { char* p = ws + o; o += (n + 255) & ~(size_t)255; return p; };
  unsigned short* WxT0 = (unsigned short*)take((size_t)G4H_ * H_ * 2);
  unsigned short* WhT0 = (unsigned short*)take((size_t)G4H_ * H_ * 2);
  unsigned short* WxT1 = (unsigned short*)take((size_t)G4H_ * H_ * 2);
  unsigned short* WhT1 = (unsigned short*)take((size_t)G4H_ * H_ * 2);
  unsigned short* WsT  = (unsigned short*)take((size_t)V_ * H_ * 2);
  unsigned short* Xemb = (unsigned short*)take((size_t)BT_ * H_ * 2);
  float*          Gbuf = (float*)take((size_t)BT_ * G4H_ * 4);
  unsigned short* Hb0  = (unsigned short*)take((size_t)BT_ * H_ * 2);
  unsigned short* Hb1  = (unsigned short*)take((size_t)BT_ * H_ * 2);
  // Xemb region aliases (Xemb dead after the L0 x-part GEMM):
  char* xregion = (char*)Xemb;
  float*    gf0   = (float*)(xregion);                    // 524,288 B
  float*    gf1   = (float*)(xregion + 524288);           // 524,288 B
  unsigned* bars  = (unsigned*)(xregion + 1048576);       //  40,960 B
  float*    lseb  = (float*)(xregion + 1089536);          //  16,384 B
  float*    part4 = (float*)(xregion + 1105920);          // 4,194,304 B (4096x128 float2)
  float*    lsepart = (float*)Gbuf;                       // fallback: 500-partial layout

  const dim3 tb(32, 8);
  k_transpose_cast<<<dim3(128, 32),  tb, 0, stream>>>(W,                    WxT0, 1024, 4096, 4096);
  k_transpose_cast<<<dim3(128, 32),  tb, 0, stream>>>(W + 1024 * 4096,      WhT0, 1024, 4096, 4096);
  k_transpose_cast<<<dim3(128, 32),  tb, 0, stream>>>(W + 2048 * 4096,      WxT1, 1024, 4096, 4096);
  k_transpose_cast<<<dim3(128, 32),  tb, 0, stream>>>(W + 3072 * 4096,      WhT1, 1024, 4096, 4096);
  k_transpose_cast<<<dim3(1000, 32), tb, 0, stream>>>(sw,                   WsT,  1024, V_,  V_);

  k_gather<<<BT_, 256, 0, stream>>>(ids, emb, Xemb);
  k_gemm_bt<<<dim3(32, 32), 256, 0, stream>>>(Xemb, WxT0, brnn, Gbuf, BT_, G4H_, H_, nullptr);

  hipMemsetAsync(bars, 0, 40960, stream);

  const float* G_ = Gbuf;
  const unsigned short* Wh0_ = WhT0; const unsigned short* Wx1_ = WxT1; const unsigned short* Wh1_ = WhT1;
  const float* b1_ = brnn + 4096;
  const float* g0_ = lng; const float* bb0_ = lnb;
  float* gf0_ = gf0; float* gf1_ = gf1;
  unsigned short* H0_ = Hb0; unsigned short* H1_ = Hb1;
  unsigned* bars_ = bars;
  const unsigned short* WsT_ = WsT; const float* sb_ = sb;
  float* out_ = out; float* part_ = part4;

  void* args4[] = {&G_, &Wh0_, &Wx1_, &Wh1_, &b1_, &g0_, &bb0_, &gf0_, &gf1_,
                   &H0_, &H1_, &bars_, &WsT_, &sb_, &out_, &part_};
  hipError_t ce = hipLaunchCooperativeKernel((void*)k_lstm4, dim3(256), dim3(256), args4, 0, stream);
  if (ce == hipSuccess) {
    k_lse_finishN<<<BT_, 256, 0, stream>>>(part4, lseb, 128, 128);
  } else {
    // fallback: proven layer-split LSTM + external projection GEMM
    void* args3[] = {&G_, &Wh0_, &Wx1_, &Wh1_, &b1_, &g0_, &bb0_, &gf0_, &gf1_, &H0_, &H1_, &bars_};
    hipLaunchCooperativeKernel((void*)k_lstm3, dim3(256), dim3(256), args3, 0, stream);
    k_gemm_bt<<<dim3(250, 32), 256, 0, stream>>>(Hb1, WsT, sb, out, BT_, V_, H_, lsepart);
    k_lse_finishN<<<BT_, 256, 0, stream>>>(lsepart, lseb, 512, 500);
  }
  k_loss<<<1, 256, 0, stream>>>(out, lseb, tgt, out);
}

// Round 16
// 2126.052 us; speedup vs baseline: 1.7481x; 1.7481x over previous
//
#include <hip/hip_runtime.h>
#include <hip/hip_cooperative_groups.h>

#define V_    32000
#define B_    32
#define T_    128
#define H_    1024
#define BT_   4096     // B_*T_
#define G4H_  4096     // 4*H_
#define EPS_  1e-5f
#define FB_   1.0f     // forget bias

typedef __bf16  bf16x8 __attribute__((ext_vector_type(8)));
typedef float   f32x4  __attribute__((ext_vector_type(4)));
typedef float   f32x2  __attribute__((ext_vector_type(2)));
typedef unsigned u32x2 __attribute__((ext_vector_type(2)));
typedef short   short8 __attribute__((ext_vector_type(8)));

__device__ __forceinline__ unsigned short f2bf(float f) {
  unsigned u = __builtin_bit_cast(unsigned, f);
  u = u + 0x7FFFu + ((u >> 16) & 1u);          // round-to-nearest-even
  return (unsigned short)(u >> 16);
}
__device__ __forceinline__ float sigm(float x) { return 1.0f / (1.0f + expf(-x)); }

// ---------------------------------------------------------------- LLC-coherent access
__device__ __forceinline__ short8 ldg_coh16(const unsigned short* p) {
  short8 v;
  asm volatile("global_load_dwordx4 %0, %1, off sc0 sc1" : "=v"(v) : "v"(p) : "memory");
  return v;
}
__device__ __forceinline__ f32x4 ldg_coh16f(const float* p) {
  f32x4 v;
  asm volatile("global_load_dwordx4 %0, %1, off sc0 sc1" : "=v"(v) : "v"(p) : "memory");
  return v;
}
__device__ __forceinline__ void stg_coh8f(float* p, f32x2 v) {
  asm volatile("global_store_dwordx2 %0, %1, off sc0 sc1" :: "v"(p), "v"(v) : "memory");
}
__device__ __forceinline__ void stg_coh16f(float* p, f32x4 v) {
  asm volatile("global_store_dwordx4 %0, %1, off sc0 sc1" :: "v"(p), "v"(v) : "memory");
}
__device__ __forceinline__ void stg_coh8u(unsigned short* p, u32x2 v) {
  asm volatile("global_store_dwordx2 %0, %1, off sc0 sc1" :: "v"(p), "v"(v) : "memory");
}
__device__ __forceinline__ void vmwait0() {
  asm volatile("s_waitcnt vmcnt(0)" ::: "memory");
  __builtin_amdgcn_sched_barrier(0);           // rule #18: pin consumers after the wait
}

// ---------------------------------------------------------------- dataflow flag sync
__device__ __forceinline__ void wait_flags(unsigned* flags, int nslots, unsigned tgt) {
  const int lane = threadIdx.x & 63;
  for (;;) {
    unsigned v = 0xFFFFFFFFu;
    for (int s = lane; s < nslots; s += 64) {
      const unsigned x = __hip_atomic_load(&flags[16 * s], __ATOMIC_RELAXED, __HIP_MEMORY_SCOPE_AGENT);
      v = x < v ? x : v;
    }
    if (__all((int)(v >= tgt))) break;
    __builtin_amdgcn_s_sleep(1);
  }
}

// ---------------------------------------------------------------- transpose+cast
__global__ void k_transpose_cast(const float* __restrict__ in, unsigned short* __restrict__ out,
                                 int R, int C, int ldin) {
  __shared__ float tl[32][33];
  const int tx = threadIdx.x, ty = threadIdx.y;
  const int r0 = blockIdx.y * 32, c0 = blockIdx.x * 32;
#pragma unroll
  for (int i = 0; i < 4; ++i)
    tl[ty + 8 * i][tx] = in[(size_t)(r0 + ty + 8 * i) * ldin + c0 + tx];
  __syncthreads();
#pragma unroll
  for (int i = 0; i < 4; ++i)
    out[(size_t)(c0 + ty + 8 * i) * R + r0 + tx] = f2bf(tl[tx][ty + 8 * i]);
}

// ---------------------------------------------------------------- embedding gather
__global__ void k_gather(const int* __restrict__ ids, const float* __restrict__ emb,
                         unsigned short* __restrict__ x) {
  const int r = blockIdx.x;
  const int t4 = threadIdx.x * 4;
  const int row = ids[r];
  const float4 v = *(const float4*)&emb[(size_t)row * H_ + t4];
  ushort4 o;
  o.x = f2bf(v.x); o.y = f2bf(v.y); o.z = f2bf(v.z); o.w = f2bf(v.w);
  *(ushort4*)&x[(size_t)r * H_ + t4] = o;
}

// ---------------------------------------------------------------- bf16 GEMM, C = A * BT^T + bias
// width-16 global_load_lds staging; XCD-aware bijective block swizzle; optional
// fused per-row online-LSE partials -> lse_part[row*512 + bx*2 + wc] float2.
__global__ __launch_bounds__(256)
void k_gemm_bt(const unsigned short* __restrict__ A, const unsigned short* __restrict__ BT,
               const float* __restrict__ bias, float* __restrict__ C,
               int M, int N, int K, float* __restrict__ lse_part) {
  __shared__ unsigned short As[128 * 32];
  __shared__ unsigned short Bs[128 * 32];
  const int tid = threadIdx.x;
  const int lane = tid & 63, wid = tid >> 6;
  const int wr = wid >> 1, wc = wid & 1;
  const int la = lane & 15, lb = lane >> 4;

  int flat = blockIdx.y * gridDim.x + blockIdx.x;
  const int nwg = gridDim.x * gridDim.y;       // divisible by 8 at all call sites
  const int cpx = nwg >> 3;
  flat = (flat & 7) * cpx + (flat >> 3);
  const int bx = flat % gridDim.x, by = flat / gridDim.x;
  const int m0 = by * 128, n0 = bx * 128;

  f32x4 acc[4][4];
#pragma unroll
  for (int i = 0; i < 4; ++i)
#pragma unroll
    for (int j = 0; j < 4; ++j) acc[i][j] = f32x4{0.f, 0.f, 0.f, 0.f};

  for (int k0 = 0; k0 < K; k0 += 32) {
    __syncthreads();
#pragma unroll
    for (int i = 0; i < 2; ++i) {
      const int off = i * 2048 + tid * 8;
      const int row = off >> 5, col = off & 31;
      __builtin_amdgcn_global_load_lds(
          (const __attribute__((address_space(1))) void*)&A[(size_t)(m0 + row) * K + k0 + col],
          (__attribute__((address_space(3))) void*)&As[off], 16, 0, 0);
      __builtin_amdgcn_global_load_lds(
          (const __attribute__((address_space(1))) void*)&BT[(size_t)(n0 + row) * K + k0 + col],
          (__attribute__((address_space(3))) void*)&Bs[off], 16, 0, 0);
    }
    __syncthreads();
    bf16x8 a[4], b[4];
#pragma unroll
    for (int mm = 0; mm < 4; ++mm) a[mm] = *(bf16x8*)&As[(wr * 64 + mm * 16 + la) * 32 + lb * 8];
#pragma unroll
    for (int nn = 0; nn < 4; ++nn) b[nn] = *(bf16x8*)&Bs[(wc * 64 + nn * 16 + la) * 32 + lb * 8];
#pragma unroll
    for (int mm = 0; mm < 4; ++mm)
#pragma unroll
      for (int nn = 0; nn < 4; ++nn)
        acc[mm][nn] = __builtin_amdgcn_mfma_f32_16x16x32_bf16(a[mm], b[nn], acc[mm][nn], 0, 0, 0);
  }
#pragma unroll
  for (int mm = 0; mm < 4; ++mm)
#pragma unroll
    for (int nn = 0; nn < 4; ++nn) {
      const int row = m0 + wr * 64 + mm * 16 + lb * 4;
      const int col = n0 + wc * 64 + nn * 16 + la;
      const float bs = bias ? bias[col] : 0.f;
#pragma unroll
      for (int r = 0; r < 4; ++r)
        C[(size_t)(row + r) * N + col] = acc[mm][nn][r] + bs;
    }

  if (lse_part) {
#pragma unroll
    for (int mm = 0; mm < 4; ++mm)
#pragma unroll
      for (int r = 0; r < 4; ++r) {
        float vv[4];
        float mx = -1e30f;
#pragma unroll
        for (int nn = 0; nn < 4; ++nn) {
          vv[nn] = acc[mm][nn][r] + (bias ? bias[n0 + wc * 64 + nn * 16 + la] : 0.f);
          mx = fmaxf(mx, vv[nn]);
        }
        float ss = 0.f;
#pragma unroll
        for (int nn = 0; nn < 4; ++nn) ss += __expf(vv[nn] - mx);
#pragma unroll
        for (int msk = 1; msk < 16; msk <<= 1) {
          const float m2 = __shfl_xor(mx, msk);
          const float s2 = __shfl_xor(ss, msk);
          const float nm = fmaxf(mx, m2);
          ss = ss * __expf(mx - nm) + s2 * __expf(m2 - nm);
          mx = nm;
        }
        if (la == 0) {
          const int row = m0 + wr * 64 + mm * 16 + lb * 4 + r;
          *(float2*)&lse_part[((size_t)row * 512 + (size_t)bx * 2 + wc) * 2] = float2{mx, ss};
        }
      }
  }
}

// ---------------------------------------------------------------- shared LN+pointwise body
__device__ __forceinline__ void lstm_pointwise(
    const float* gfp, const float* g_, const float* b_, float* crow, float* rsc,
    unsigned short* hout, int tid, int lane, int w) {
  const int e0 = tid * 4;
  const f32x4 iv = ldg_coh16f(&gfp[e0]);
  const f32x4 jv = ldg_coh16f(&gfp[1024 + e0]);
  const f32x4 fv = ldg_coh16f(&gfp[2048 + e0]);
  const f32x4 ov = ldg_coh16f(&gfp[3072 + e0]);
  vmwait0();

  float vals[8] = {0, 0, 0, 0, 0, 0, 0, 0};
#pragma unroll
  for (int u = 0; u < 4; ++u) {
    vals[0] += iv[u]; vals[4] += iv[u] * iv[u];
    vals[1] += jv[u]; vals[5] += jv[u] * jv[u];
    vals[2] += fv[u]; vals[6] += fv[u] * fv[u];
    vals[3] += ov[u]; vals[7] += ov[u] * ov[u];
  }
#pragma unroll
  for (int i = 0; i < 8; ++i) {
    float x = vals[i];
    for (int off = 32; off > 0; off >>= 1) x += __shfl_down(x, off);
    if (lane == 0) rsc[w * 8 + i] = x;
  }
  __syncthreads();
#pragma unroll
  for (int i = 0; i < 8; ++i)
    vals[i] = rsc[i] + rsc[8 + i] + rsc[16 + i] + rsc[24 + i];
  __syncthreads();
  const float m0 = vals[0] * (1.f / 1024), m1 = vals[1] * (1.f / 1024);
  const float m2 = vals[2] * (1.f / 1024), m3 = vals[3] * (1.f / 1024);
  const float r0 = rsqrtf(vals[4] * (1.f / 1024) - m0 * m0 + EPS_);
  const float r1 = rsqrtf(vals[5] * (1.f / 1024) - m1 * m1 + EPS_);
  const float r2 = rsqrtf(vals[6] * (1.f / 1024) - m2 * m2 + EPS_);
  const float r3 = rsqrtf(vals[7] * (1.f / 1024) - m3 * m3 + EPS_);

  const float4 gI = *(const float4*)&g_[e0];
  const float4 gJ = *(const float4*)&g_[1024 + e0];
  const float4 gF = *(const float4*)&g_[2048 + e0];
  const float4 gO = *(const float4*)&g_[3072 + e0];
  const float4 gC = *(const float4*)&g_[4096 + e0];
  const float4 bI = *(const float4*)&b_[e0];
  const float4 bJ = *(const float4*)&b_[1024 + e0];
  const float4 bF = *(const float4*)&b_[2048 + e0];
  const float4 bO = *(const float4*)&b_[3072 + e0];
  const float4 bC = *(const float4*)&b_[4096 + e0];
  const float4 cr = *(const float4*)&crow[e0];

  float nc[4], oo[4];
  float cs = 0.f, cq = 0.f;
  {
    const float gi[4] = {gI.x, gI.y, gI.z, gI.w}, bi[4] = {bI.x, bI.y, bI.z, bI.w};
    const float gj[4] = {gJ.x, gJ.y, gJ.z, gJ.w}, bj[4] = {bJ.x, bJ.y, bJ.z, bJ.w};
    const float gff[4] = {gF.x, gF.y, gF.z, gF.w}, bf[4] = {bF.x, bF.y, bF.z, bF.w};
    const float go[4] = {gO.x, gO.y, gO.z, gO.w}, bo[4] = {bO.x, bO.y, bO.z, bO.w};
    const float cv[4] = {cr.x, cr.y, cr.z, cr.w};
#pragma unroll
    for (int u = 0; u < 4; ++u) {
      const float xi = gi[u] * ((iv[u] - m0) * r0) + bi[u];
      const float xj = gj[u] * ((jv[u] - m1) * r1) + bj[u];
      const float xf = gff[u] * ((fv[u] - m2) * r2) + bf[u];
      const float xo = go[u] * ((ov[u] - m3) * r3) + bo[u];
      const float ncv = cv[u] * sigm(xf + FB_) + sigm(xi) * tanhf(xj);
      nc[u] = ncv; oo[u] = xo;
      cs += ncv; cq += ncv * ncv;
    }
  }
  {
    float x = cs, y = cq;
    for (int off = 32; off > 0; off >>= 1) { x += __shfl_down(x, off); y += __shfl_down(y, off); }
    if (lane == 0) { rsc[w * 2] = x; rsc[w * 2 + 1] = y; }
  }
  __syncthreads();
  cs = rsc[0] + rsc[2] + rsc[4] + rsc[6];
  cq = rsc[1] + rsc[3] + rsc[5] + rsc[7];
  const float mc = cs * (1.f / 1024);
  const float rc = rsqrtf(cq * (1.f / 1024) - mc * mc + EPS_);
  {
    const float gc[4] = {gC.x, gC.y, gC.z, gC.w}, bc[4] = {bC.x, bC.y, bC.z, bC.w};
    unsigned short hb[4];
#pragma unroll
    for (int u = 0; u < 4; ++u) {
      const float nh = tanhf(gc[u] * ((nc[u] - mc) * rc) + bc[u]) * sigm(oo[u]);
      hb[u] = f2bf(nh);
    }
    u32x2 hv;
    hv[0] = (unsigned)hb[0] | ((unsigned)hb[1] << 16);
    hv[1] = (unsigned)hb[2] | ((unsigned)hb[3] << 16);
    stg_coh8u(&hout[e0], hv);
    *(float4*)&crow[e0] = float4{nc[0], nc[1], nc[2], nc[3]};
  }
  __syncthreads();                           // drain h stores before flag
}

// ---------------------------------------------------------------- layer-split fused LSTM (r13-proven)
// Blocks 0-127: L0, 32 gate-cols each (Wh0 64KB LDS). Blocks 128-255: L1, 32
// cols each (Wx1+Wh1 128KB LDS). P2-L0 on blocks 0-31; P2-L1 on blocks 128-159.
// Separate flag arrays take L1's matmul work OFF L0's recurrence-critical path.
// Flags: g0[128]@0, g1[128]@+2048w, h0[32]@+4096w, h1[32]@+4608w.
__global__ __launch_bounds__(256)
void k_lstm3(const float* __restrict__ G, const unsigned short* __restrict__ WhT0,
             const unsigned short* __restrict__ WxT1, const unsigned short* __restrict__ WhT1,
             const float* __restrict__ b1,
             const float* __restrict__ lng, const float* __restrict__ lnb,
             float* __restrict__ gf0, float* __restrict__ gf1,
             unsigned short* __restrict__ Hb0, unsigned short* __restrict__ Hb1,
             unsigned* flags) {
  __shared__ unsigned short wA[32 * 1024];   // L0: Wh0 | L1: Wx1  (swizzled rows)
  __shared__ unsigned short wB[32 * 1024];   // L1: Wh1 (unused by L0 blocks)
  __shared__ float red[4][32][32];
  __shared__ float crow[1024];
  __shared__ float rsc[64];

  const int tid = threadIdx.x, bid = blockIdx.x;
  const int lane = tid & 63, w = tid >> 6;
  const int la = lane & 15, lb = lane >> 4;
  const bool isL1 = (bid >= 128);
  const int cb = (isL1 ? (bid - 128) : bid) * 32;    // gate-col base
  unsigned* flag_g0 = flags;                  // 128 slots
  unsigned* flag_g1 = flags + 2048;           // 128 slots
  unsigned* flag_h0 = flags + 4096;           // 32 slots
  unsigned* flag_h1 = flags + 4608;           // 32 slots

  for (int i = tid * 8; i < 32 * 1024; i += 2048) {
    const int cl = i >> 10, k = i & 1023;
    const int dst = cl * 1024 + (k ^ ((cl & 7) << 3));
    if (!isL1) {
      *(short8*)&wA[dst] = *(const short8*)&WhT0[(size_t)(cb + cl) * 1024 + k];
    } else {
      *(short8*)&wA[dst] = *(const short8*)&WxT1[(size_t)(cb + cl) * 1024 + k];
      *(short8*)&wB[dst] = *(const short8*)&WhT1[(size_t)(cb + cl) * 1024 + k];
    }
  }
  if (bid < 32 || (bid >= 128 && bid < 160))
    for (int e = tid; e < 1024; e += 256) crow[e] = 0.0f;
  __syncthreads();

  for (int s = 0; s <= T_; ++s) {
    // ---- dependency waits (block-uniform)
    if (w == 0) {
      if (!isL1) {
        if (s >= 1 && s < T_) wait_flags(flag_h0, 32, (unsigned)s);
      } else {
        if (s >= 1) wait_flags(flag_h0, 32, (unsigned)s);
        if (s >= 2) wait_flags(flag_h1, 32, (unsigned)(s - 1));
      }
    }
    __syncthreads();

    // ---- matmul
    f32x4 acc[2][2] = {{{0.f,0.f,0.f,0.f},{0.f,0.f,0.f,0.f}},{{0.f,0.f,0.f,0.f},{0.f,0.f,0.f,0.f}}};
    const int kw = w * 256 + lb * 8;
    if (!isL1) {
      if (s >= 1 && s < T_) {
        const size_t t0 = (size_t)(s - 1);
#pragma unroll
        for (int half = 0; half < 2; ++half) {
          short8 a0[4], a1[4];
          const int kb = kw + half * 128;
#pragma unroll
          for (int kk = 0; kk < 4; ++kk) {
            a0[kk] = ldg_coh16(&Hb0[((size_t)la * T_ + t0) * H_ + kb + kk * 32]);
            a1[kk] = ldg_coh16(&Hb0[((size_t)(16 + la) * T_ + t0) * H_ + kb + kk * 32]);
          }
          vmwait0();
#pragma unroll
          for (int kk = 0; kk < 4; ++kk) {
            const int kx = (kb + kk * 32) ^ ((la & 7) << 3);
            const bf16x8 b0 = *(bf16x8*)&wA[la * 1024 + kx];
            const bf16x8 b1v = *(bf16x8*)&wA[(16 + la) * 1024 + kx];
            const bf16x8 va0 = __builtin_bit_cast(bf16x8, a0[kk]);
            const bf16x8 va1 = __builtin_bit_cast(bf16x8, a1[kk]);
            acc[0][0] = __builtin_amdgcn_mfma_f32_16x16x32_bf16(va0, b0, acc[0][0], 0, 0, 0);
            acc[0][1] = __builtin_amdgcn_mfma_f32_16x16x32_bf16(va0, b1v, acc[0][1], 0, 0, 0);
            acc[1][0] = __builtin_amdgcn_mfma_f32_16x16x32_bf16(va1, b0, acc[1][0], 0, 0, 0);
            acc[1][1] = __builtin_amdgcn_mfma_f32_16x16x32_bf16(va1, b1v, acc[1][1], 0, 0, 0);
          }
        }
      }
    } else if (s >= 1) {
      const size_t t0 = (size_t)(s - 1);
#pragma unroll
      for (int half = 0; half < 2; ++half) {       // h0 @ Wx1
        short8 a0[4], a1[4];
        const int kb = kw + half * 128;
#pragma unroll
        for (int kk = 0; kk < 4; ++kk) {
          a0[kk] = ldg_coh16(&Hb0[((size_t)la * T_ + t0) * H_ + kb + kk * 32]);
          a1[kk] = ldg_coh16(&Hb0[((size_t)(16 + la) * T_ + t0) * H_ + kb + kk * 32]);
        }
        vmwait0();
#pragma unroll
        for (int kk = 0; kk < 4; ++kk) {
          const int kx = (kb + kk * 32) ^ ((la & 7) << 3);
          const bf16x8 b0 = *(bf16x8*)&wA[la * 1024 + kx];
          const bf16x8 b1v = *(bf16x8*)&wA[(16 + la) * 1024 + kx];
          const bf16x8 va0 = __builtin_bit_cast(bf16x8, a0[kk]);
          const bf16x8 va1 = __builtin_bit_cast(bf16x8, a1[kk]);
          acc[0][0] = __builtin_amdgcn_mfma_f32_16x16x32_bf16(va0, b0, acc[0][0], 0, 0, 0);
          acc[0][1] = __builtin_amdgcn_mfma_f32_16x16x32_bf16(va0, b1v, acc[0][1], 0, 0, 0);
          acc[1][0] = __builtin_amdgcn_mfma_f32_16x16x32_bf16(va1, b0, acc[1][0], 0, 0, 0);
          acc[1][1] = __builtin_amdgcn_mfma_f32_16x16x32_bf16(va1, b1v, acc[1][1], 0, 0, 0);
        }
      }
      if (s >= 2) {
        const size_t t1 = (size_t)(s - 2);
#pragma unroll
        for (int half = 0; half < 2; ++half) {     // h1 @ Wh1
          short8 a0[4], a1[4];
          const int kb = kw + half * 128;
#pragma unroll
          for (int kk = 0; kk < 4; ++kk) {
            a0[kk] = ldg_coh16(&Hb1[((size_t)la * T_ + t1) * H_ + kb + kk * 32]);
            a1[kk] = ldg_coh16(&Hb1[((size_t)(16 + la) * T_ + t1) * H_ + kb + kk * 32]);
          }
          vmwait0();
#pragma unroll
          for (int kk = 0; kk < 4; ++kk) {
            const int kx = (kb + kk * 32) ^ ((la & 7) << 3);
            const bf16x8 b0 = *(bf16x8*)&wB[la * 1024 + kx];
            const bf16x8 b1v = *(bf16x8*)&wB[(16 + la) * 1024 + kx];
            const bf16x8 va0 = __builtin_bit_cast(bf16x8, a0[kk]);
            const bf16x8 va1 = __builtin_bit_cast(bf16x8, a1[kk]);
            acc[0][0] = __builtin_amdgcn_mfma_f32_16x16x32_bf16(va0, b0, acc[0][0], 0, 0, 0);
            acc[0][1] = __builtin_amdgcn_mfma_f32_16x16x32_bf16(va0, b1v, acc[0][1], 0, 0, 0);
            acc[1][0] = __builtin_amdgcn_mfma_f32_16x16x32_bf16(va1, b0, acc[1][0], 0, 0, 0);
            acc[1][1] = __builtin_amdgcn_mfma_f32_16x16x32_bf16(va1, b1v, acc[1][1], 0, 0, 0);
          }
        }
      }
    }

    // ---- reduce + store gf (block-uniform guard)
    const bool doStore = isL1 ? (s >= 1) : (s < T_);
    if (doStore) {
#pragma unroll
      for (int half = 0; half < 2; ++half)
#pragma unroll
        for (int cg = 0; cg < 2; ++cg)
#pragma unroll
          for (int r = 0; r < 4; ++r)
            red[w][half * 16 + lb * 4 + r][cg * 16 + la] = acc[half][cg][r];
      __syncthreads();
      const int b2 = tid >> 3, c4 = (tid & 7) * 4;
      f32x4 sv = *(f32x4*)&red[0][b2][c4];
      sv += *(f32x4*)&red[1][b2][c4];
      sv += *(f32x4*)&red[2][b2][c4];
      sv += *(f32x4*)&red[3][b2][c4];
      if (!isL1) {
        sv += *(const f32x4*)&G[((size_t)(b2 * T_ + s)) * G4H_ + cb + c4];
        stg_coh16f(&gf0[(size_t)b2 * G4H_ + cb + c4], sv);
      } else {
        sv += *(const f32x4*)&b1[cb + c4];
        stg_coh16f(&gf1[(size_t)b2 * G4H_ + cb + c4], sv);
      }
      __syncthreads();                       // drain gf stores + red consumed
      if (tid == 0) {
        if (!isL1)
          __hip_atomic_store(&flag_g0[16 * bid], (unsigned)(s + 1), __ATOMIC_RELAXED, __HIP_MEMORY_SCOPE_AGENT);
        else
          __hip_atomic_store(&flag_g1[16 * (bid - 128)], (unsigned)(s + 1), __ATOMIC_RELAXED, __HIP_MEMORY_SCOPE_AGENT);
      }
    }

    // ---- phase 2 (block-uniform guard)
    const bool doP2 = (!isL1) ? (bid < 32 && s < T_) : (bid < 160 && s >= 1);
    if (doP2) {
      const int b = isL1 ? (bid - 128) : bid;
      if (w == 0) wait_flags(isL1 ? flag_g1 : flag_g0, 128, (unsigned)(s + 1));
      __syncthreads();
      const float* gfp = (isL1 ? gf1 : gf0) + (size_t)b * G4H_;
      const float* g_ = isL1 ? (lng + 5120) : lng;
      const float* b_ = isL1 ? (lnb + 5120) : lnb;
      const int tt = isL1 ? (s - 1) : s;
      unsigned short* hout = (isL1 ? Hb1 : Hb0) + ((size_t)b * T_ + tt) * H_;
      lstm_pointwise(gfp, g_, b_, crow, rsc, hout, tid, lane, w);
      if (tid == 0) {
        if (isL1)
          __hip_atomic_store(&flag_h1[16 * b], (unsigned)s, __ATOMIC_RELAXED, __HIP_MEMORY_SCOPE_AGENT);
        else
          __hip_atomic_store(&flag_h0[16 * b], (unsigned)(s + 1), __ATOMIC_RELAXED, __HIP_MEMORY_SCOPE_AGENT);
      }
    }
  }
}

// ---------------------------------------------------------------- LSE finish
__global__ __launch_bounds__(256)
void k_lse_finish(const float* __restrict__ part, float* __restrict__ lse) {
  __shared__ float rm[4];
  __shared__ float rs[4];
  const int r = blockIdx.x, tid = threadIdx.x;
  const int lane = tid & 63, w = tid >> 6;
  float m = -1e30f, s = 0.f;
  for (int i = tid; i < 500; i += 256) {
    const float2 p = *(const float2*)&part[((size_t)r * 512 + i) * 2];
    const float nm = fmaxf(m, p.x);
    s = s * __expf(m - nm) + p.y * __expf(p.x - nm);
    m = nm;
  }
  for (int off = 32; off > 0; off >>= 1) {
    const float m2 = __shfl_down(m, off), s2 = __shfl_down(s, off);
    const float nm = fmaxf(m, m2);
    s = s * __expf(m - nm) + s2 * __expf(m2 - nm);
    m = nm;
  }
  if (lane == 0) { rm[w] = m; rs[w] = s; }
  __syncthreads();
  if (tid == 0) {
    float M = rm[0], S = rs[0];
#pragma unroll
    for (int i = 1; i < 4; ++i) {
      const float nm = fmaxf(M, rm[i]);
      S = S * __expf(M - nm) + rs[i] * __expf(rm[i] - nm);
      M = nm;
    }
    lse[r] = M + logf(S);
  }
}

// ---------------------------------------------------------------- loss (mean NLL)
__global__ __launch_bounds__(256)
void k_loss(const float* __restrict__ logits, const float* __restrict__ lse,
            const int* __restrict__ tgt, float* __restrict__ out) {
  __shared__ float rsc[4];
  const int tid = threadIdx.x;
  float s = 0.f;
  for (int r = tid; r < BT_; r += 256)
    s += lse[r] - logits[(size_t)r * V_ + tgt[r]];
  for (int off = 32; off > 0; off >>= 1) s += __shfl_down(s, off);
  if ((tid & 63) == 0) rsc[tid >> 6] = s;
  __syncthreads();
  if (tid == 0) out[(size_t)BT_ * V_] = (rsc[0] + rsc[1] + rsc[2] + rsc[3]) / (float)BT_;
}

// ================================================================ launch
// r13-proven configuration (resubmitted verbatim after an infrastructure-only
// failure in r15: container died before the bench ran; same source passed r13
// at 2126 us). Layer-split cooperative LSTM (k_lstm3) + external projection
// GEMM with fused LSE partials. ws ~191.4 MB (budget ~192 MB): gf0/gf1/bars/
// lseb alias Xemb (dead after L0 x-GEMM); LSE partials alias Gbuf (dead after
// LSTM).
extern "C" void kernel_launch(void* const* d_in, const int* in_sizes, int n_in,
                              void* d_out, int out_size, void* d_ws, size_t ws_size,
                              hipStream_t stream) {
  const int*   ids  = (const int*)d_in[0];
  const int*   tgt  = (const int*)d_in[1];
  const float* emb  = (const float*)d_in[2];
  const float* W    = (const float*)d_in[3];   // [2][2048][4096]
  const float* brnn = (const float*)d_in[4];   // [2][4096]
  const float* lng  = (const float*)d_in[5];   // [2][5][1024]
  const float* lnb  = (const float*)d_in[6];
  const float* sw   = (const float*)d_in[7];   // [1024][32000]
  const float* sb   = (const float*)d_in[8];   // [32000]
  float* out = (float*)d_out;

  char* ws = (char*)d_ws;
  size_t o = 0;
  auto take = [&](size_t n) { char* p = ws + o; o += (n + 255) & ~(size_t)255; return p; };
  unsigned short* WxT0 = (unsigned short*)take((size_t)G4H_ * H_ * 2);
  unsigned short* WhT0 = (unsigned short*)take((size_t)G4H_ * H_ * 2);
  unsigned short* WxT1 = (unsigned short*)take((size_t)G4H_ * H_ * 2);
  unsigned short* WhT1 = (unsigned short*)take((size_t)G4H_ * H_ * 2);
  unsigned short* WsT  = (unsigned short*)take((size_t)V_ * H_ * 2);
  unsigned short* Xemb = (unsigned short*)take((size_t)BT_ * H_ * 2);
  float*          Gbuf = (float*)take((size_t)BT_ * G4H_ * 4);
  unsigned short* Hb0  = (unsigned short*)take((size_t)BT_ * H_ * 2);
  unsigned short* Hb1  = (unsigned short*)take((size_t)BT_ * H_ * 2);
  char* xregion = (char*)Xemb;
  float*    gf0  = (float*)(xregion);
  float*    gf1  = (float*)(xregion + 524288);
  unsigned* bars = (unsigned*)(xregion + 1048576);
  float*    lseb = (float*)(xregion + 1089536);
  float*    lsepart = (float*)Gbuf;            // 16 MB, aliases Gbuf after LSTM

  const dim3 tb(32, 8);
  k_transpose_cast<<<dim3(128, 32),  tb, 0, stream>>>(W,                    WxT0, 1024, 4096, 4096);
  k_transpose_cast<<<dim3(128, 32),  tb, 0, stream>>>(W + 1024 * 4096,      WhT0, 1024, 4096, 4096);
  k_transpose_cast<<<dim3(128, 32),  tb, 0, stream>>>(W + 2048 * 4096,      WxT1, 1024, 4096, 4096);
  k_transpose_cast<<<dim3(128, 32),  tb, 0, stream>>>(W + 3072 * 4096,      WhT1, 1024, 4096, 4096);
  k_transpose_cast<<<dim3(1000, 32), tb, 0, stream>>>(sw,                   WsT,  1024, V_,  V_);

  k_gather<<<BT_, 256, 0, stream>>>(ids, emb, Xemb);
  k_gemm_bt<<<dim3(32, 32), 256, 0, stream>>>(Xemb, WxT0, brnn, Gbuf, BT_, G4H_, H_, nullptr);

  hipMemsetAsync(bars, 0, 40960, stream);

  const float* G_ = Gbuf;
  const unsigned short* Wh0_ = WhT0; const unsigned short* Wx1_ = WxT1; const unsigned short* Wh1_ = WhT1;
  const float* b1_ = brnn + 4096;
  const float* g0_ = lng; const float* bb0_ = lnb;
  float* gf0_ = gf0; float* gf1_ = gf1;
  unsigned short* H0_ = Hb0; unsigned short* H1_ = Hb1;
  unsigned* bars_ = bars;
  void* args[] = {&G_, &Wh0_, &Wx1_, &Wh1_, &b1_, &g0_, &bb0_, &gf0_, &gf1_, &H0_, &H1_, &bars_};

  hipLaunchCooperativeKernel((void*)k_lstm3, dim3(256), dim3(256), args, 0, stream);

  k_gemm_bt<<<dim3(250, 32), 256, 0, stream>>>(Hb1, WsT, sb, out, BT_, V_, H_, lsepart);
  k_lse_finish<<<BT_, 256, 0, stream>>>(lsepart, lseb);
  k_loss<<<1, 256, 0, stream>>>(out, lseb, tgt, out);
}